// Round 10
// baseline (104.341 us; speedup 1.0000x reference)
//
#include <hip/hip_runtime.h>
#include <hip/hip_bf16.h>
#include <stdint.h>
#include <math.h>

typedef __attribute__((ext_vector_type(8))) short short8;
typedef __attribute__((ext_vector_type(4))) short short4v;
typedef __attribute__((ext_vector_type(4))) float float4v;

#define MFMA16(a,b,c) __builtin_amdgcn_mfma_f32_16x16x32_bf16((a),(b),(c),0,0,0)

__device__ __forceinline__ short bf16r(float f) {
  union { float f; uint32_t u; } v; v.f = f;
  uint32_t r = v.u + 0x7fffu + ((v.u >> 16) & 1u);
  return (short)(r >> 16);
}
__device__ __forceinline__ float bf2f(short s) {
  union { float f; uint32_t u; } v; v.u = ((uint32_t)(uint16_t)s) << 16;
  return v.f;
}
// packed f32x2 -> bf16x2 (lo = a, hi = b)
__device__ __forceinline__ uint32_t cvtpk(float a, float b) {
  uint32_t r;
  asm("v_cvt_pk_bf16_f32 %0, %1, %2" : "=v"(r) : "v"(a), "v"(b));
  return r;
}

__device__ __forceinline__ void gld_lds16(void* lds, const void* g) {
  __builtin_amdgcn_global_load_lds(
      (const __attribute__((address_space(1))) uint32_t*)g,
      (__attribute__((address_space(3))) uint32_t*)lds, 16, 0, 0);
}

// ---------------- Kernel 1: W transpose+convert (LDS transpose) -------------
__global__ __launch_bounds__(256) void prep_wt(
    const float* __restrict__ Wk, const float* __restrict__ Wq,
    const float* __restrict__ Wv, short* __restrict__ WT) {
  __shared__ float tile[64][65];
  const int w = blockIdx.y;
  const int k0 = blockIdx.x * 64;
  const float* W = (w == 0) ? Wk : (w == 1) ? Wq : Wv;
  const int tid = threadIdx.x;
#pragma unroll
  for (int i = 0; i < 16; ++i) {
    int e = i * 256 + tid;
    int kk = e >> 6, hh = e & 63;
    tile[kk][hh] = W[(size_t)(k0 + kk) * 64 + hh];
  }
  __syncthreads();
#pragma unroll
  for (int i = 0; i < 16; ++i) {
    int e = i * 256 + tid;
    int hh = e >> 6, kk = e & 63;
    WT[(size_t)w * 65536 + hh * 1024 + k0 + kk] = bf16r(tile[kk][hh]);
  }
}

// ---------------- Kernel 2: projection GEMM, 8 waves, double-buffered -------
// BM=64, 512 thr = 8 waves; wave w: m-tiles 2*(w&1)+{0,1}, n-tiles 3*(w>>1)+
// {0,1,2}. Per K-step: issue stage(next) -> compute(cur) -> barrier.
__global__ __launch_bounds__(512) void proj_kernel(
    const float* __restrict__ x, const short* __restrict__ WT,
    short* __restrict__ Kg, short* __restrict__ Qg, short* __restrict__ Vt) {
  __shared__ __align__(16) short xs[2][64][72];
  __shared__ __align__(16) short wts[2][192 * 64];
  const int tid = threadIdx.x;
  const int lane = tid & 63;
  const int w = tid >> 6;
  const int c = lane & 15;
  const int sl = lane >> 4;
  const int mh = w & 1;                          // m-pair
  const int nh = w >> 1;                         // n-triple (0..3)
  const int m0 = blockIdx.x * 64;

  float4v acc[2][3];
#pragma unroll
  for (int mi = 0; mi < 2; ++mi)
#pragma unroll
    for (int ni = 0; ni < 3; ++ni) acc[mi][ni] = (float4v){0.f, 0.f, 0.f, 0.f};

  const int srow = tid >> 3;                     // 0..63
  const int scol = (tid & 7) * 8;                // 8 floats/thread
  const float* xrow = x + (size_t)(m0 + srow) * 1024 + scol;

#define PSTAGE_WT(buf, kk)                                                    \
  _Pragma("unroll") for (int rr = 0; rr < 3; ++rr) {                          \
    const int chunk = rr * 512 + tid;                                         \
    const int n = chunk >> 3;                                                 \
    const int cc = chunk & 7;                                                 \
    gld_lds16(wts[buf] + chunk * 8,                                           \
              WT + (size_t)n * 1024 + (kk) + ((cc ^ (n & 7)) * 8));           \
  }
#define PWRITE_X(buf)                                                         \
  {                                                                           \
    short8 hx;                                                                \
    hx[0] = bf16r(xr0.x); hx[1] = bf16r(xr0.y);                               \
    hx[2] = bf16r(xr0.z); hx[3] = bf16r(xr0.w);                               \
    hx[4] = bf16r(xr1.x); hx[5] = bf16r(xr1.y);                               \
    hx[6] = bf16r(xr1.z); hx[7] = bf16r(xr1.w);                               \
    *(short8*)(&xs[buf][srow][scol]) = hx;                                    \
  }

  float4v xr0 = *(const float4v*)(xrow);
  float4v xr1 = *(const float4v*)(xrow + 4);
  float4v xn0 = *(const float4v*)(xrow + 64);
  float4v xn1 = *(const float4v*)(xrow + 68);

  PSTAGE_WT(0, 0)
  PWRITE_X(0)
  __syncthreads();

  int cur = 0;
  for (int it = 0; it < 16; ++it) {
    const int k0 = it * 64;
    if (it + 1 < 16) {
      PSTAGE_WT(cur ^ 1, k0 + 64)
      xr0 = xn0; xr1 = xn1;
      PWRITE_X(cur ^ 1)
      if (it + 2 < 16) {
        xn0 = *(const float4v*)(xrow + k0 + 128);
        xn1 = *(const float4v*)(xrow + k0 + 132);
      }
    }
    // compute from cur
    short8 a[2][2];
#pragma unroll
    for (int mi = 0; mi < 2; ++mi) {
      const int mr = (mh * 2 + mi) * 16 + c;
      a[mi][0] = *(const short8*)(&xs[cur][mr][sl * 8]);
      a[mi][1] = *(const short8*)(&xs[cur][mr][32 + sl * 8]);
    }
#pragma unroll
    for (int ni = 0; ni < 3; ++ni) {
      const int rw = (nh * 3 + ni) * 16 + c;
      short8 b0 = *(const short8*)(wts[cur] + rw * 64 + ((sl ^ (rw & 7)) * 8));
      short8 b1 = *(const short8*)(wts[cur] + rw * 64 + (((sl + 4) ^ (rw & 7)) * 8));
#pragma unroll
      for (int mi = 0; mi < 2; ++mi) {
        acc[mi][ni] = MFMA16(a[mi][0], b0, acc[mi][ni]);
        acc[mi][ni] = MFMA16(a[mi][1], b1, acc[mi][ni]);
      }
    }
    __syncthreads();
    cur ^= 1;
  }
#undef PSTAGE_WT
#undef PWRITE_X

  const int b = m0 >> 12;
  const int s_base = m0 & 4095;
#pragma unroll
  for (int ni = 0; ni < 3; ++ni) {
    const int nt = nh * 3 + ni;
    const int wsel = nt >> 2;                    // 0:K 1:Q 2:V
    const int h = (nt & 3) * 16 + c;
#pragma unroll
    for (int mi = 0; mi < 2; ++mi) {
      const int q_local = (mh * 2 + mi) * 16 + sl * 4;
      if (wsel == 2) {
        short4v pv;
        pv.x = bf16r(acc[mi][ni].x); pv.y = bf16r(acc[mi][ni].y);
        pv.z = bf16r(acc[mi][ni].z); pv.w = bf16r(acc[mi][ni].w);
        *(short4v*)(Vt + (size_t)(b * 64 + h) * 4096 + s_base + q_local) = pv;
      } else if (wsel == 1) {
#pragma unroll
        for (int i = 0; i < 4; ++i)
          Qg[(size_t)(m0 + q_local + i) * 64 + h] = bf16r(acc[mi][ni][i] * 0.125f);
      } else {
#pragma unroll
        for (int i = 0; i < 4; ++i)
          Kg[(size_t)(m0 + q_local + i) * 64 + h] = bf16r(acc[mi][ni][i]);
      }
    }
  }
}

// ---------------- Kernel 3: flash attention + fused combine -----------------
// 256 thr = 4 waves, QB=128 (32 rows/wave). Swapped QK (mfma(K,Q)) -> S^T in
// lanes (q = c); in-register P via cvt_pk + shfl; LDS = KV dbuf only (4
// blocks/CU). XCD-affinity remap. LAST chunk of each (b,g) combines partials
// (device-scope atomic + agent fences; fixed summation order = deterministic).
#define SLOT_BYTES 16896   // 128*64 bf16 o (16384) + 128 f32 l (512)
__global__ __launch_bounds__(256, 4) void attn_kernel(
    const short* __restrict__ Qg, const short* __restrict__ Kg,
    const short* __restrict__ Vt, float* __restrict__ out,
    char* __restrict__ part, int* __restrict__ cnt, int split) {
  __shared__ __align__(16) short Ks[2][64 * 64];
  __shared__ __align__(16) short Vs[2][64 * 64];
  __shared__ int lastFlag;
  const int tid = threadIdx.x;
  const int lane = tid & 63;
  const int w = tid >> 6;
  const int c = lane & 15;
  const int sl = lane >> 4;

  // ---- unit decode: F(g) = ceil((g+1)/2)*ceil((g+2)/2), nch = g/2+1 ----
  int g, ch, b, uu = 0;
  if (split) {
    const int lin = (blockIdx.x & 7) * 136 + (blockIdx.x >> 3);  // XCD affinity
    b = lin / 272;
    uu = lin - b * 272;
    g = (int)(2.0f * sqrtf((float)uu));
    while (((g + 2) >> 1) * ((g + 3) >> 1) <= uu) ++g;
    while (((g + 1) >> 1) * ((g + 2) >> 1) > uu) --g;
    ch = uu - ((g + 1) >> 1) * ((g + 2) >> 1);
  } else { g = blockIdx.x; b = blockIdx.y; ch = 0; }
  const int T = 2 * (g + 1);
  const int c0 = ch * 4;
  const int c1 = (!split || c0 + 4 > T) ? T : c0 + 4;
  const int nch = split ? ((g >> 1) + 1) : 1;
  const int qw = g * 128 + w * 32;

  const short* Kb = Kg + (size_t)b * 4096 * 64;
  const short* Vb = Vt + (size_t)b * 64 * 4096;

  // Q frags (MFMA B-operand): lane holds Q[q=qw+qf*16+c][h=sl*8+:8]
  short8 aq[2][2];
#pragma unroll
  for (int qf = 0; qf < 2; ++qf) {
    const short* qp = Qg + (size_t)(b * 4096 + qw + qf * 16 + c) * 64 + sl * 8;
    aq[qf][0] = *(const short8*)(qp);
    aq[qf][1] = *(const short8*)(qp + 32);
  }

  float4v o[2][4];
#pragma unroll
  for (int qf = 0; qf < 2; ++qf)
#pragma unroll
    for (int ht = 0; ht < 4; ++ht) o[qf][ht] = (float4v){0.f, 0.f, 0.f, 0.f};
  float lsum[2] = {0.f, 0.f};

#define STAGE(buf, t)                                                        \
  {                                                                          \
    const int kv0s = (t) * 64;                                               \
    _Pragma("unroll")                                                        \
    for (int j = 0; j < 2; ++j) {                                            \
      const int chunk = j * 256 + tid;                                       \
      const int rw = chunk >> 3;                                             \
      const int scol = ((chunk & 7) ^ (rw & 7)) * 8;                         \
      gld_lds16(Ks[buf] + chunk * 8, Kb + (size_t)(kv0s + rw) * 64 + scol);  \
      gld_lds16(Vs[buf] + chunk * 8, Vb + (size_t)rw * 4096 + kv0s + scol);  \
    }                                                                        \
  }

  STAGE(0, c0)
  __syncthreads();

  const int srcA = c + 32 * (sl & 1);     // shfl source for A-frag regs 0,1
  const int srcB = srcA + 16;             // for regs 2,3

  int cur = 0;
  for (int t = c0; t < c1; ++t) {
    const int kv0 = t * 64;
    if (t + 1 < c1) STAGE(cur ^ 1, t + 1)

    const short* KsC = Ks[cur];
    const short* VsC = Vs[cur];

    // S^T = K Q^T: lane (c,sl) holds S[kv=kv0+16nt+4sl+i][q=qw+16qf+c]
    float4v s[2][4];
    __builtin_amdgcn_s_setprio(1);
#pragma unroll
    for (int nt = 0; nt < 4; ++nt) {
      const int rw = nt * 16 + c;
      short8 kb0 = *(const short8*)(KsC + rw * 64 + ((sl ^ (rw & 7)) * 8));
      short8 kb1 = *(const short8*)(KsC + rw * 64 + (((sl + 4) ^ (rw & 7)) * 8));
#pragma unroll
      for (int qf = 0; qf < 2; ++qf) {
        float4v z = {0.f, 0.f, 0.f, 0.f};
        z = MFMA16(kb0, aq[qf][0], z);
        z = MFMA16(kb1, aq[qf][1], z);
        s[qf][nt] = z;
      }
    }
    __builtin_amdgcn_s_setprio(0);

    // causal mask
    if (kv0 + 63 > qw) {
#pragma unroll
      for (int nt = 0; nt < 4; ++nt)
#pragma unroll
        for (int i = 0; i < 4; ++i) {
          const int kvg = kv0 + nt * 16 + sl * 4 + i;
#pragma unroll
          for (int qf = 0; qf < 2; ++qf) {
            const int qg = qw + qf * 16 + c;
            s[qf][nt][i] = (kvg <= qg) ? s[qf][nt][i] : -1e30f;
          }
        }
    }

    // P = exp(s) (implicit max 0), in-lane lsum, pack pairs to bf16x2
    uint32_t tpk[2][4][2];
#pragma unroll
    for (int qf = 0; qf < 2; ++qf)
#pragma unroll
      for (int nt = 0; nt < 4; ++nt) {
        const float p0 = __expf(s[qf][nt][0]);
        const float p1 = __expf(s[qf][nt][1]);
        const float p2 = __expf(s[qf][nt][2]);
        const float p3 = __expf(s[qf][nt][3]);
        lsum[qf] += (p0 + p1) + (p2 + p3);
        tpk[qf][nt][0] = cvtpk(p0, p1);
        tpk[qf][nt][1] = cvtpk(p2, p3);
      }

    // redistribute to PV A-frag layout (verified index algebra):
    // ap[qf][f] reg r holds P[q=qw+16qf+c][kv = kv0+32f+8sl+2r+{0,1}]
    short8 ap[2][2];
#pragma unroll
    for (int qf = 0; qf < 2; ++qf)
#pragma unroll
      for (int f = 0; f < 2; ++f) {
        const uint32_t q0a = __shfl((int)tpk[qf][2 * f][0], srcA);
        const uint32_t q0b = __shfl((int)tpk[qf][2 * f + 1][0], srcA);
        const uint32_t q1a = __shfl((int)tpk[qf][2 * f][1], srcA);
        const uint32_t q1b = __shfl((int)tpk[qf][2 * f + 1][1], srcA);
        const uint32_t q2a = __shfl((int)tpk[qf][2 * f][0], srcB);
        const uint32_t q2b = __shfl((int)tpk[qf][2 * f + 1][0], srcB);
        const uint32_t q3a = __shfl((int)tpk[qf][2 * f][1], srcB);
        const uint32_t q3b = __shfl((int)tpk[qf][2 * f + 1][1], srcB);
        const bool lo = (sl < 2);
        union { uint32_t u[4]; short8 s8; } ua;
        ua.u[0] = lo ? q0a : q0b;
        ua.u[1] = lo ? q1a : q1b;
        ua.u[2] = lo ? q2a : q2b;
        ua.u[3] = lo ? q3a : q3b;
        ap[qf][f] = ua.s8;
      }

    // O += P V
    __builtin_amdgcn_s_setprio(1);
#pragma unroll
    for (int ht = 0; ht < 4; ++ht) {
      const int rw = ht * 16 + c;
      short8 vb0 = *(const short8*)(VsC + rw * 64 + ((sl ^ (rw & 7)) * 8));
      short8 vb1 = *(const short8*)(VsC + rw * 64 + (((sl + 4) ^ (rw & 7)) * 8));
#pragma unroll
      for (int qf = 0; qf < 2; ++qf) {
        o[qf][ht] = MFMA16(ap[qf][0], vb0, o[qf][ht]);
        o[qf][ht] = MFMA16(ap[qf][1], vb1, o[qf][ht]);
      }
    }
    __builtin_amdgcn_s_setprio(0);

    if (t + 1 < c1) __syncthreads();
    cur ^= 1;
  }
#undef STAGE

  // full row sums (reduce across the 4 sl-lanes sharing q=c)
  float rsum[2];
#pragma unroll
  for (int qf = 0; qf < 2; ++qf) {
    float r = lsum[qf];
    r += __shfl_xor(r, 16);
    r += __shfl_xor(r, 32);
    rsum[qf] = r;
  }

  if (nch == 1) {                                // single chunk: direct out
    float inv[2][4];
#pragma unroll
    for (int qf = 0; qf < 2; ++qf)
#pragma unroll
      for (int i = 0; i < 4; ++i)
        inv[qf][i] = 1.0f / __shfl(rsum[qf], sl * 4 + i);
#pragma unroll
    for (int qf = 0; qf < 2; ++qf)
#pragma unroll
      for (int ht = 0; ht < 4; ++ht)
#pragma unroll
        for (int i = 0; i < 4; ++i) {
          const int q = qw + qf * 16 + sl * 4 + i;
          out[(size_t)(b * 4096 + q) * 64 + ht * 16 + c] = o[qf][ht][i] * inv[qf][i];
        }
    return;
  }

  // partial write (bf16 o + f32 l)
  short* sp = (short*)(part + (size_t)(b * 272 + uu) * SLOT_BYTES);
  float* lp = (float*)(sp + 8192);
#pragma unroll
  for (int qf = 0; qf < 2; ++qf)
#pragma unroll
    for (int ht = 0; ht < 4; ++ht)
#pragma unroll
      for (int i = 0; i < 4; ++i) {
        const int row = w * 32 + qf * 16 + sl * 4 + i;
        sp[row * 64 + ht * 16 + c] = bf16r(o[qf][ht][i]);
      }
  if (sl == 0) {
#pragma unroll
    for (int qf = 0; qf < 2; ++qf)
      lp[w * 32 + qf * 16 + c] = rsum[qf];
  }

  // ---- last chunk of (b,g) combines ----
  __syncthreads();
  if (tid == 0) {
    __builtin_amdgcn_fence(__ATOMIC_RELEASE, "agent");
    int old = __hip_atomic_fetch_add(&cnt[b * 32 + g], 1,
                                     __ATOMIC_RELAXED, __HIP_MEMORY_SCOPE_AGENT);
    lastFlag = (old == nch - 1);
  }
  __syncthreads();
  if (!lastFlag) return;
  __builtin_amdgcn_fence(__ATOMIC_ACQUIRE, "agent");

  const int F = ((g + 1) >> 1) * ((g + 2) >> 1);
  const char* base = part + (size_t)(b * 272 + F) * SLOT_BYTES;
  const int r = tid >> 1;                        // 0..127
  const int hb = (tid & 1) * 32;

  float L = 0.f;
  float acc[32];
#pragma unroll
  for (int k = 0; k < 32; ++k) acc[k] = 0.f;
  for (int i = 0; i < nch; ++i) {
    const short* spp = (const short*)(base + (size_t)i * SLOT_BYTES);
    L += ((const float*)(spp + 8192))[r];
    const short* sr = spp + r * 64 + hb;
#pragma unroll
    for (int k = 0; k < 4; ++k) {
      short8 v = *(const short8*)(sr + k * 8);
#pragma unroll
      for (int j = 0; j < 8; ++j) acc[k * 8 + j] += bf2f(v[j]);
    }
  }
  const float inv = 1.0f / L;
  float* op = out + (size_t)(b * 4096 + g * 128 + r) * 64 + hb;
#pragma unroll
  for (int k = 0; k < 8; ++k) {
    float4v res = {acc[k * 4] * inv, acc[k * 4 + 1] * inv,
                   acc[k * 4 + 2] * inv, acc[k * 4 + 3] * inv};
    *(float4v*)(op + k * 4) = res;
  }
}

extern "C" void kernel_launch(void* const* d_in, const int* in_sizes, int n_in,
                              void* d_out, int out_size, void* d_ws, size_t ws_size,
                              hipStream_t stream) {
  const float* x  = (const float*)d_in[0];
  const float* Wk = (const float*)d_in[1];
  const float* Wq = (const float*)d_in[2];
  const float* Wv = (const float*)d_in[3];

  char* ws = (char*)d_ws;
  short* WT = (short*)ws;                                  // 393216 B
  short* Kg = (short*)(ws + 393216);                       // 2 MB
  short* Qg = (short*)(ws + 393216 + 2097152);             // 2 MB
  short* Vt = (short*)(ws + 393216 + 2 * 2097152);         // 2 MB
  const size_t part_off = 393216 + 3 * 2097152;            // 6684672
  char* part = ws + part_off;
  const size_t cnt_off = part_off + (size_t)1088 * SLOT_BYTES;
  int* cnt = (int*)(ws + cnt_off);                         // 128 ints

  const int split = (ws_size >= cnt_off + 512) ? 1 : 0;

  prep_wt<<<dim3(16, 3), dim3(256), 0, stream>>>(Wk, Wq, Wv, WT);
  if (split) hipMemsetAsync(cnt, 0, 512, stream);
  proj_kernel<<<dim3(256), dim3(512), 0, stream>>>(x, WT, Kg, Qg, Vt);
  attn_kernel<<<split ? dim3(1088) : dim3(32, 4), dim3(256), 0, stream>>>(
      Qg, Kg, Vt, (float*)d_out, part, cnt, split);
}

// Round 11
// 60.928 us; speedup vs baseline: 1.7125x; 1.7125x over previous
//
#include <hip/hip_runtime.h>
#include <hip/hip_bf16.h>
#include <stdint.h>
#include <math.h>

typedef __attribute__((ext_vector_type(8))) short short8;
typedef __attribute__((ext_vector_type(4))) short short4v;
typedef __attribute__((ext_vector_type(4))) float float4v;

#define MFMA16(a,b,c) __builtin_amdgcn_mfma_f32_16x16x32_bf16((a),(b),(c),0,0,0)

__device__ __forceinline__ short bf16r(float f) {
  union { float f; uint32_t u; } v; v.f = f;
  uint32_t r = v.u + 0x7fffu + ((v.u >> 16) & 1u);
  return (short)(r >> 16);
}
__device__ __forceinline__ float bf2f(short s) {
  union { float f; uint32_t u; } v; v.u = ((uint32_t)(uint16_t)s) << 16;
  return v.f;
}
// packed f32x2 -> bf16x2 (lo = a, hi = b)
__device__ __forceinline__ uint32_t cvtpk(float a, float b) {
  uint32_t r;
  asm("v_cvt_pk_bf16_f32 %0, %1, %2" : "=v"(r) : "v"(a), "v"(b));
  return r;
}

__device__ __forceinline__ void gld_lds16(void* lds, const void* g) {
  __builtin_amdgcn_global_load_lds(
      (const __attribute__((address_space(1))) uint32_t*)g,
      (__attribute__((address_space(3))) uint32_t*)lds, 16, 0, 0);
}

// ---------------- Kernel 1: W transpose+convert (LDS transpose) -------------
__global__ __launch_bounds__(256) void prep_wt(
    const float* __restrict__ Wk, const float* __restrict__ Wq,
    const float* __restrict__ Wv, short* __restrict__ WT) {
  __shared__ float tile[64][65];
  const int w = blockIdx.y;
  const int k0 = blockIdx.x * 64;
  const float* W = (w == 0) ? Wk : (w == 1) ? Wq : Wv;
  const int tid = threadIdx.x;
#pragma unroll
  for (int i = 0; i < 16; ++i) {
    int e = i * 256 + tid;
    int kk = e >> 6, hh = e & 63;
    tile[kk][hh] = W[(size_t)(k0 + kk) * 64 + hh];
  }
  __syncthreads();
#pragma unroll
  for (int i = 0; i < 16; ++i) {
    int e = i * 256 + tid;
    int hh = e >> 6, kk = e & 63;
    WT[(size_t)w * 65536 + hh * 1024 + k0 + kk] = bf16r(tile[kk][hh]);
  }
}

// ---------------- Kernel 2: projection GEMM, 8 waves, double-buffered -------
// (validated in R10) BM=64, 512 thr = 8 waves; wave w: m-tiles 2*(w&1)+{0,1},
// n-tiles 3*(w>>1)+{0,1,2}. Per K-step: stage(next) -> compute(cur) -> barrier.
__global__ __launch_bounds__(512) void proj_kernel(
    const float* __restrict__ x, const short* __restrict__ WT,
    short* __restrict__ Kg, short* __restrict__ Qg, short* __restrict__ Vt) {
  __shared__ __align__(16) short xs[2][64][72];
  __shared__ __align__(16) short wts[2][192 * 64];
  const int tid = threadIdx.x;
  const int lane = tid & 63;
  const int w = tid >> 6;
  const int c = lane & 15;
  const int sl = lane >> 4;
  const int mh = w & 1;
  const int nh = w >> 1;
  const int m0 = blockIdx.x * 64;

  float4v acc[2][3];
#pragma unroll
  for (int mi = 0; mi < 2; ++mi)
#pragma unroll
    for (int ni = 0; ni < 3; ++ni) acc[mi][ni] = (float4v){0.f, 0.f, 0.f, 0.f};

  const int srow = tid >> 3;
  const int scol = (tid & 7) * 8;
  const float* xrow = x + (size_t)(m0 + srow) * 1024 + scol;

#define PSTAGE_WT(buf, kk)                                                    \
  _Pragma("unroll") for (int rr = 0; rr < 3; ++rr) {                          \
    const int chunk = rr * 512 + tid;                                         \
    const int n = chunk >> 3;                                                 \
    const int cc = chunk & 7;                                                 \
    gld_lds16(wts[buf] + chunk * 8,                                           \
              WT + (size_t)n * 1024 + (kk) + ((cc ^ (n & 7)) * 8));           \
  }
#define PWRITE_X(buf)                                                         \
  {                                                                           \
    short8 hx;                                                                \
    hx[0] = bf16r(xr0.x); hx[1] = bf16r(xr0.y);                               \
    hx[2] = bf16r(xr0.z); hx[3] = bf16r(xr0.w);                               \
    hx[4] = bf16r(xr1.x); hx[5] = bf16r(xr1.y);                               \
    hx[6] = bf16r(xr1.z); hx[7] = bf16r(xr1.w);                               \
    *(short8*)(&xs[buf][srow][scol]) = hx;                                    \
  }

  float4v xr0 = *(const float4v*)(xrow);
  float4v xr1 = *(const float4v*)(xrow + 4);
  float4v xn0 = *(const float4v*)(xrow + 64);
  float4v xn1 = *(const float4v*)(xrow + 68);

  PSTAGE_WT(0, 0)
  PWRITE_X(0)
  __syncthreads();

  int cur = 0;
  for (int it = 0; it < 16; ++it) {
    const int k0 = it * 64;
    if (it + 1 < 16) {
      PSTAGE_WT(cur ^ 1, k0 + 64)
      xr0 = xn0; xr1 = xn1;
      PWRITE_X(cur ^ 1)
      if (it + 2 < 16) {
        xn0 = *(const float4v*)(xrow + k0 + 128);
        xn1 = *(const float4v*)(xrow + k0 + 132);
      }
    }
    short8 a[2][2];
#pragma unroll
    for (int mi = 0; mi < 2; ++mi) {
      const int mr = (mh * 2 + mi) * 16 + c;
      a[mi][0] = *(const short8*)(&xs[cur][mr][sl * 8]);
      a[mi][1] = *(const short8*)(&xs[cur][mr][32 + sl * 8]);
    }
#pragma unroll
    for (int ni = 0; ni < 3; ++ni) {
      const int rw = (nh * 3 + ni) * 16 + c;
      short8 b0 = *(const short8*)(wts[cur] + rw * 64 + ((sl ^ (rw & 7)) * 8));
      short8 b1 = *(const short8*)(wts[cur] + rw * 64 + (((sl + 4) ^ (rw & 7)) * 8));
#pragma unroll
      for (int mi = 0; mi < 2; ++mi) {
        acc[mi][ni] = MFMA16(a[mi][0], b0, acc[mi][ni]);
        acc[mi][ni] = MFMA16(a[mi][1], b1, acc[mi][ni]);
      }
    }
    __syncthreads();
    cur ^= 1;
  }
#undef PSTAGE_WT
#undef PWRITE_X

  const int b = m0 >> 12;
  const int s_base = m0 & 4095;
#pragma unroll
  for (int ni = 0; ni < 3; ++ni) {
    const int nt = nh * 3 + ni;
    const int wsel = nt >> 2;                    // 0:K 1:Q 2:V
    const int h = (nt & 3) * 16 + c;
#pragma unroll
    for (int mi = 0; mi < 2; ++mi) {
      const int q_local = (mh * 2 + mi) * 16 + sl * 4;
      if (wsel == 2) {
        short4v pv;
        pv.x = bf16r(acc[mi][ni].x); pv.y = bf16r(acc[mi][ni].y);
        pv.z = bf16r(acc[mi][ni].z); pv.w = bf16r(acc[mi][ni].w);
        *(short4v*)(Vt + (size_t)(b * 64 + h) * 4096 + s_base + q_local) = pv;
      } else if (wsel == 1) {
#pragma unroll
        for (int i = 0; i < 4; ++i)
          Qg[(size_t)(m0 + q_local + i) * 64 + h] = bf16r(acc[mi][ni][i] * 0.125f);
      } else {
#pragma unroll
        for (int i = 0; i < 4; ++i)
          Kg[(size_t)(m0 + q_local + i) * 64 + h] = bf16r(acc[mi][ni][i]);
      }
    }
  }
}

// ---------------- Kernel 3: flash attention (R9, validated 69us) ------------
// 256 thr = 4 waves, QB=128 (32 rows/wave). Swapped QK -> S^T in lanes;
// in-register P via cvt_pk + shfl; LDS = KV dbuf only; XCD-affinity remap.
// NOTE: do NOT fuse combine here — R10 showed the tail + (256,4) collapses
// VGPR to 64 and spills the main loop (86us).
#define SLOT_BYTES 16896   // 128*64 bf16 o (16384) + 128 f32 l (512)
__global__ __launch_bounds__(256, 4) void attn_kernel(
    const short* __restrict__ Qg, const short* __restrict__ Kg,
    const short* __restrict__ Vt, float* __restrict__ out,
    char* __restrict__ part, int split) {
  __shared__ __align__(16) short Ks[2][64 * 64];
  __shared__ __align__(16) short Vs[2][64 * 64];
  const int tid = threadIdx.x;
  const int lane = tid & 63;
  const int w = tid >> 6;
  const int c = lane & 15;
  const int sl = lane >> 4;

  // ---- unit decode: F(g) = ceil((g+1)/2)*ceil((g+2)/2), nch = g/2+1 ----
  int g, ch, b, uu = 0;
  if (split) {
    const int lin = (blockIdx.x & 7) * 136 + (blockIdx.x >> 3);  // XCD affinity
    b = lin / 272;
    uu = lin - b * 272;
    g = (int)(2.0f * sqrtf((float)uu));
    while (((g + 2) >> 1) * ((g + 3) >> 1) <= uu) ++g;
    while (((g + 1) >> 1) * ((g + 2) >> 1) > uu) --g;
    ch = uu - ((g + 1) >> 1) * ((g + 2) >> 1);
  } else { g = blockIdx.x; b = blockIdx.y; ch = 0; }
  const int T = 2 * (g + 1);
  const int c0 = ch * 4;
  const int c1 = (!split || c0 + 4 > T) ? T : c0 + 4;
  const int nch = split ? ((g >> 1) + 1) : 1;
  const int qw = g * 128 + w * 32;

  const short* Kb = Kg + (size_t)b * 4096 * 64;
  const short* Vb = Vt + (size_t)b * 64 * 4096;

  short8 aq[2][2];
#pragma unroll
  for (int qf = 0; qf < 2; ++qf) {
    const short* qp = Qg + (size_t)(b * 4096 + qw + qf * 16 + c) * 64 + sl * 8;
    aq[qf][0] = *(const short8*)(qp);
    aq[qf][1] = *(const short8*)(qp + 32);
  }

  float4v o[2][4];
#pragma unroll
  for (int qf = 0; qf < 2; ++qf)
#pragma unroll
    for (int ht = 0; ht < 4; ++ht) o[qf][ht] = (float4v){0.f, 0.f, 0.f, 0.f};
  float lsum[2] = {0.f, 0.f};

#define STAGE(buf, t)                                                        \
  {                                                                          \
    const int kv0s = (t) * 64;                                               \
    _Pragma("unroll")                                                        \
    for (int j = 0; j < 2; ++j) {                                            \
      const int chunk = j * 256 + tid;                                       \
      const int rw = chunk >> 3;                                             \
      const int scol = ((chunk & 7) ^ (rw & 7)) * 8;                         \
      gld_lds16(Ks[buf] + chunk * 8, Kb + (size_t)(kv0s + rw) * 64 + scol);  \
      gld_lds16(Vs[buf] + chunk * 8, Vb + (size_t)rw * 4096 + kv0s + scol);  \
    }                                                                        \
  }

  STAGE(0, c0)
  __syncthreads();

  const int srcA = c + 32 * (sl & 1);
  const int srcB = srcA + 16;

  int cur = 0;
  for (int t = c0; t < c1; ++t) {
    const int kv0 = t * 64;
    if (t + 1 < c1) STAGE(cur ^ 1, t + 1)

    const short* KsC = Ks[cur];
    const short* VsC = Vs[cur];

    float4v s[2][4];
    __builtin_amdgcn_s_setprio(1);
#pragma unroll
    for (int nt = 0; nt < 4; ++nt) {
      const int rw = nt * 16 + c;
      short8 kb0 = *(const short8*)(KsC + rw * 64 + ((sl ^ (rw & 7)) * 8));
      short8 kb1 = *(const short8*)(KsC + rw * 64 + (((sl + 4) ^ (rw & 7)) * 8));
#pragma unroll
      for (int qf = 0; qf < 2; ++qf) {
        float4v z = {0.f, 0.f, 0.f, 0.f};
        z = MFMA16(kb0, aq[qf][0], z);
        z = MFMA16(kb1, aq[qf][1], z);
        s[qf][nt] = z;
      }
    }
    __builtin_amdgcn_s_setprio(0);

    if (kv0 + 63 > qw) {
#pragma unroll
      for (int nt = 0; nt < 4; ++nt)
#pragma unroll
        for (int i = 0; i < 4; ++i) {
          const int kvg = kv0 + nt * 16 + sl * 4 + i;
#pragma unroll
          for (int qf = 0; qf < 2; ++qf) {
            const int qg = qw + qf * 16 + c;
            s[qf][nt][i] = (kvg <= qg) ? s[qf][nt][i] : -1e30f;
          }
        }
    }

    uint32_t tpk[2][4][2];
#pragma unroll
    for (int qf = 0; qf < 2; ++qf)
#pragma unroll
      for (int nt = 0; nt < 4; ++nt) {
        const float p0 = __expf(s[qf][nt][0]);
        const float p1 = __expf(s[qf][nt][1]);
        const float p2 = __expf(s[qf][nt][2]);
        const float p3 = __expf(s[qf][nt][3]);
        lsum[qf] += (p0 + p1) + (p2 + p3);
        tpk[qf][nt][0] = cvtpk(p0, p1);
        tpk[qf][nt][1] = cvtpk(p2, p3);
      }

    short8 ap[2][2];
#pragma unroll
    for (int qf = 0; qf < 2; ++qf)
#pragma unroll
      for (int f = 0; f < 2; ++f) {
        const uint32_t q0a = __shfl((int)tpk[qf][2 * f][0], srcA);
        const uint32_t q0b = __shfl((int)tpk[qf][2 * f + 1][0], srcA);
        const uint32_t q1a = __shfl((int)tpk[qf][2 * f][1], srcA);
        const uint32_t q1b = __shfl((int)tpk[qf][2 * f + 1][1], srcA);
        const uint32_t q2a = __shfl((int)tpk[qf][2 * f][0], srcB);
        const uint32_t q2b = __shfl((int)tpk[qf][2 * f + 1][0], srcB);
        const uint32_t q3a = __shfl((int)tpk[qf][2 * f][1], srcB);
        const uint32_t q3b = __shfl((int)tpk[qf][2 * f + 1][1], srcB);
        const bool lo = (sl < 2);
        union { uint32_t u[4]; short8 s8; } ua;
        ua.u[0] = lo ? q0a : q0b;
        ua.u[1] = lo ? q1a : q1b;
        ua.u[2] = lo ? q2a : q2b;
        ua.u[3] = lo ? q3a : q3b;
        ap[qf][f] = ua.s8;
      }

    __builtin_amdgcn_s_setprio(1);
#pragma unroll
    for (int ht = 0; ht < 4; ++ht) {
      const int rw = ht * 16 + c;
      short8 vb0 = *(const short8*)(VsC + rw * 64 + ((sl ^ (rw & 7)) * 8));
      short8 vb1 = *(const short8*)(VsC + rw * 64 + (((sl + 4) ^ (rw & 7)) * 8));
#pragma unroll
      for (int qf = 0; qf < 2; ++qf) {
        o[qf][ht] = MFMA16(ap[qf][0], vb0, o[qf][ht]);
        o[qf][ht] = MFMA16(ap[qf][1], vb1, o[qf][ht]);
      }
    }
    __builtin_amdgcn_s_setprio(0);

    if (t + 1 < c1) __syncthreads();
    cur ^= 1;
  }
#undef STAGE

  float rsum[2];
#pragma unroll
  for (int qf = 0; qf < 2; ++qf) {
    float r = lsum[qf];
    r += __shfl_xor(r, 16);
    r += __shfl_xor(r, 32);
    rsum[qf] = r;
  }

  if (nch == 1) {
    float inv[2][4];
#pragma unroll
    for (int qf = 0; qf < 2; ++qf)
#pragma unroll
      for (int i = 0; i < 4; ++i)
        inv[qf][i] = 1.0f / __shfl(rsum[qf], sl * 4 + i);
#pragma unroll
    for (int qf = 0; qf < 2; ++qf)
#pragma unroll
      for (int ht = 0; ht < 4; ++ht)
#pragma unroll
        for (int i = 0; i < 4; ++i) {
          const int q = qw + qf * 16 + sl * 4 + i;
          out[(size_t)(b * 4096 + q) * 64 + ht * 16 + c] = o[qf][ht][i] * inv[qf][i];
        }
  } else {
    short* sp = (short*)(part + (size_t)(b * 272 + uu) * SLOT_BYTES);
    float* lp = (float*)(sp + 8192);
#pragma unroll
    for (int qf = 0; qf < 2; ++qf)
#pragma unroll
      for (int ht = 0; ht < 4; ++ht)
#pragma unroll
        for (int i = 0; i < 4; ++i) {
          const int row = w * 32 + qf * 16 + sl * 4 + i;
          sp[row * 64 + ht * 16 + c] = bf16r(o[qf][ht][i]);
        }
    if (sl == 0) {
#pragma unroll
      for (int qf = 0; qf < 2; ++qf)
        lp[w * 32 + qf * 16 + c] = rsum[qf];
    }
  }
}

// ---------------- Kernel 4: split-KV combine, row-split 4x ------------------
// grid (32, 4, 4): z = row-quarter (32 rows each). 512 blocks for latency
// hiding (R9's 128 serial-loop blocks were occupancy-starved).
__global__ __launch_bounds__(256) void combine_kernel(
    const char* __restrict__ part, float* __restrict__ out) {
  const int g = blockIdx.x;                      // 0..31
  const int b = blockIdx.y;
  const int N = (g >> 1) + 1;
  if (N == 1) return;                            // attn wrote direct
  const int F = ((g + 1) >> 1) * ((g + 2) >> 1);
  const char* base = part + (size_t)(b * 272 + F) * SLOT_BYTES;
  const int r = blockIdx.z * 32 + (threadIdx.x >> 3);   // row 0..127
  const int cb = (threadIdx.x & 7) * 8;                 // col block (8 f32)

  float L = 0.f;
  float acc[8];
#pragma unroll
  for (int k = 0; k < 8; ++k) acc[k] = 0.f;
  for (int i = 0; i < N; ++i) {
    const short* sp = (const short*)(base + (size_t)i * SLOT_BYTES);
    L += ((const float*)(sp + 8192))[r];
    short8 v = *(const short8*)(sp + r * 64 + cb);
#pragma unroll
    for (int j = 0; j < 8; ++j) acc[j] += bf2f(v[j]);
  }
  const float inv = 1.0f / L;
  float* op = out + (size_t)(b * 4096 + g * 128 + r) * 64 + cb;
  float4v r0 = {acc[0] * inv, acc[1] * inv, acc[2] * inv, acc[3] * inv};
  float4v r1 = {acc[4] * inv, acc[5] * inv, acc[6] * inv, acc[7] * inv};
  *(float4v*)(op) = r0;
  *(float4v*)(op + 4) = r1;
}

extern "C" void kernel_launch(void* const* d_in, const int* in_sizes, int n_in,
                              void* d_out, int out_size, void* d_ws, size_t ws_size,
                              hipStream_t stream) {
  const float* x  = (const float*)d_in[0];
  const float* Wk = (const float*)d_in[1];
  const float* Wq = (const float*)d_in[2];
  const float* Wv = (const float*)d_in[3];

  char* ws = (char*)d_ws;
  short* WT = (short*)ws;                                  // 393216 B
  short* Kg = (short*)(ws + 393216);                       // 2 MB
  short* Qg = (short*)(ws + 393216 + 2097152);             // 2 MB
  short* Vt = (short*)(ws + 393216 + 2 * 2097152);         // 2 MB
  const size_t part_off = 393216 + 3 * 2097152;            // 6684672
  char* part = ws + part_off;

  const int split = (ws_size >= part_off + (size_t)1088 * SLOT_BYTES) ? 1 : 0;

  prep_wt<<<dim3(16, 3), dim3(256), 0, stream>>>(Wk, Wq, Wv, WT);
  proj_kernel<<<dim3(256), dim3(512), 0, stream>>>(x, WT, Kg, Qg, Vt);
  attn_kernel<<<split ? dim3(1088) : dim3(32, 4), dim3(256), 0, stream>>>(
      Qg, Kg, Vt, (float*)d_out, part, split);
  if (split)
    combine_kernel<<<dim3(32, 4, 4), dim3(256), 0, stream>>>(part, (float*)d_out);
}

// Round 12
// 60.407 us; speedup vs baseline: 1.7273x; 1.0086x over previous
//
#include <hip/hip_runtime.h>
#include <hip/hip_bf16.h>
#include <stdint.h>
#include <math.h>

typedef __attribute__((ext_vector_type(8))) short short8;
typedef __attribute__((ext_vector_type(4))) short short4v;
typedef __attribute__((ext_vector_type(4))) float float4v;

#define MFMA16(a,b,c) __builtin_amdgcn_mfma_f32_16x16x32_bf16((a),(b),(c),0,0,0)

__device__ __forceinline__ short bf16r(float f) {
  union { float f; uint32_t u; } v; v.f = f;
  uint32_t r = v.u + 0x7fffu + ((v.u >> 16) & 1u);
  return (short)(r >> 16);
}
__device__ __forceinline__ float bf2f(short s) {
  union { float f; uint32_t u; } v; v.u = ((uint32_t)(uint16_t)s) << 16;
  return v.f;
}
// packed f32x2 -> bf16x2 (lo = a, hi = b)
__device__ __forceinline__ uint32_t cvtpk(float a, float b) {
  uint32_t r;
  asm("v_cvt_pk_bf16_f32 %0, %1, %2" : "=v"(r) : "v"(a), "v"(b));
  return r;
}

__device__ __forceinline__ void gld_lds16(void* lds, const void* g) {
  __builtin_amdgcn_global_load_lds(
      (const __attribute__((address_space(1))) uint32_t*)g,
      (__attribute__((address_space(3))) uint32_t*)lds, 16, 0, 0);
}

// ---------------- Kernel 1: W transpose+convert (LDS transpose) -------------
__global__ __launch_bounds__(256) void prep_wt(
    const float* __restrict__ Wk, const float* __restrict__ Wq,
    const float* __restrict__ Wv, short* __restrict__ WT) {
  __shared__ float tile[64][65];
  const int w = blockIdx.y;
  const int k0 = blockIdx.x * 64;
  const float* W = (w == 0) ? Wk : (w == 1) ? Wq : Wv;
  const int tid = threadIdx.x;
#pragma unroll
  for (int i = 0; i < 16; ++i) {
    int e = i * 256 + tid;
    int kk = e >> 6, hh = e & 63;
    tile[kk][hh] = W[(size_t)(k0 + kk) * 64 + hh];
  }
  __syncthreads();
#pragma unroll
  for (int i = 0; i < 16; ++i) {
    int e = i * 256 + tid;
    int hh = e >> 6, kk = e & 63;
    WT[(size_t)w * 65536 + hh * 1024 + k0 + kk] = bf16r(tile[kk][hh]);
  }
}

// ---------------- Kernel 2: projection GEMM, BM=32, 2 blocks/CU -------------
// 512 blocks x 512 thr (8 waves); wave w: m-tile w&1, n-triple w>>1.
// Per K-step: stage(next WT via gld_lds + x via reg) -> compute(cur) -> barrier.
// Qg pre-scaled by 0.125*log2(e) so attn can use native exp2.
__global__ __launch_bounds__(512, 4) void proj_kernel(
    const float* __restrict__ x, const short* __restrict__ WT,
    short* __restrict__ Kg, short* __restrict__ Qg, short* __restrict__ Vt) {
  __shared__ __align__(16) short xs[2][32][72];
  __shared__ __align__(16) short wts[2][192 * 64];
  const int tid = threadIdx.x;
  const int lane = tid & 63;
  const int w = tid >> 6;
  const int c = lane & 15;
  const int sl = lane >> 4;
  const int mh = w & 1;                          // m-tile (16 rows)
  const int nh = w >> 1;                         // n-triple (0..3)
  const int m0 = blockIdx.x * 32;

  float4v acc[3];
#pragma unroll
  for (int ni = 0; ni < 3; ++ni) acc[ni] = (float4v){0.f, 0.f, 0.f, 0.f};

  const int srow = tid >> 4;                     // 0..31
  const int scol = (tid & 15) * 4;               // 4 floats/thread
  const float* xrow = x + (size_t)(m0 + srow) * 1024 + scol;

#define PSTAGE_WT(buf, kk)                                                    \
  _Pragma("unroll") for (int rr = 0; rr < 3; ++rr) {                          \
    const int chunk = rr * 512 + tid;                                         \
    const int n = chunk >> 3;                                                 \
    const int cc = chunk & 7;                                                 \
    gld_lds16(wts[buf] + chunk * 8,                                           \
              WT + (size_t)n * 1024 + (kk) + ((cc ^ (n & 7)) * 8));           \
  }
#define PWRITE_X(buf)                                                         \
  {                                                                           \
    short4v hx;                                                               \
    hx.x = bf16r(xr.x); hx.y = bf16r(xr.y);                                   \
    hx.z = bf16r(xr.z); hx.w = bf16r(xr.w);                                   \
    *(short4v*)(&xs[buf][srow][scol]) = hx;                                   \
  }

  float4v xr = *(const float4v*)(xrow);
  float4v xn = *(const float4v*)(xrow + 64);

  PSTAGE_WT(0, 0)
  PWRITE_X(0)
  __syncthreads();

  int cur = 0;
  for (int it = 0; it < 16; ++it) {
    const int k0 = it * 64;
    if (it + 1 < 16) {
      PSTAGE_WT(cur ^ 1, k0 + 64)
      xr = xn;
      PWRITE_X(cur ^ 1)
      if (it + 2 < 16) xn = *(const float4v*)(xrow + k0 + 128);
    }
    // compute from cur
    short8 a0 = *(const short8*)(&xs[cur][mh * 16 + c][sl * 8]);
    short8 a1 = *(const short8*)(&xs[cur][mh * 16 + c][32 + sl * 8]);
#pragma unroll
    for (int ni = 0; ni < 3; ++ni) {
      const int rw = (nh * 3 + ni) * 16 + c;
      short8 b0 = *(const short8*)(wts[cur] + rw * 64 + ((sl ^ (rw & 7)) * 8));
      short8 b1 = *(const short8*)(wts[cur] + rw * 64 + (((sl + 4) ^ (rw & 7)) * 8));
      acc[ni] = MFMA16(a0, b0, acc[ni]);
      acc[ni] = MFMA16(a1, b1, acc[ni]);
    }
    __syncthreads();
    cur ^= 1;
  }
#undef PSTAGE_WT
#undef PWRITE_X

  const int b = m0 >> 12;
  const int s_base = m0 & 4095;
  const float QSCALE = 0.18033688011112042f;     // 0.125 * log2(e)
#pragma unroll
  for (int ni = 0; ni < 3; ++ni) {
    const int nt = nh * 3 + ni;
    const int wsel = nt >> 2;                    // 0:K 1:Q 2:V
    const int h = (nt & 3) * 16 + c;
    const int q_local = mh * 16 + sl * 4;
    if (wsel == 2) {
      short4v pv;
      pv.x = bf16r(acc[ni].x); pv.y = bf16r(acc[ni].y);
      pv.z = bf16r(acc[ni].z); pv.w = bf16r(acc[ni].w);
      *(short4v*)(Vt + (size_t)(b * 64 + h) * 4096 + s_base + q_local) = pv;
    } else if (wsel == 1) {
#pragma unroll
      for (int i = 0; i < 4; ++i)
        Qg[(size_t)(m0 + q_local + i) * 64 + h] = bf16r(acc[ni][i] * QSCALE);
    } else {
#pragma unroll
      for (int i = 0; i < 4; ++i)
        Kg[(size_t)(m0 + q_local + i) * 64 + h] = bf16r(acc[ni][i]);
    }
  }
}

// ---------------- Kernel 3: flash attention (R9/R11 validated) --------------
// 256 thr = 4 waves, QB=128 (32 rows/wave). Swapped QK -> S^T in lanes;
// in-register P via cvt_pk + shfl; LDS = KV dbuf only; XCD-affinity remap.
// exp2 softmax (ln2 folded into Qg at proj). Do NOT fuse combine (R10: VGPR
// collapse to 64 + spills at (256,4)).
#define SLOT_BYTES 16896   // 128*64 bf16 o (16384) + 128 f32 l (512)
__global__ __launch_bounds__(256, 4) void attn_kernel(
    const short* __restrict__ Qg, const short* __restrict__ Kg,
    const short* __restrict__ Vt, float* __restrict__ out,
    char* __restrict__ part, int split) {
  __shared__ __align__(16) short Ks[2][64 * 64];
  __shared__ __align__(16) short Vs[2][64 * 64];
  const int tid = threadIdx.x;
  const int lane = tid & 63;
  const int w = tid >> 6;
  const int c = lane & 15;
  const int sl = lane >> 4;

  // ---- unit decode: F(g) = ceil((g+1)/2)*ceil((g+2)/2), nch = g/2+1 ----
  int g, ch, b, uu = 0;
  if (split) {
    const int lin = (blockIdx.x & 7) * 136 + (blockIdx.x >> 3);  // XCD affinity
    b = lin / 272;
    uu = lin - b * 272;
    g = (int)(2.0f * sqrtf((float)uu));
    while (((g + 2) >> 1) * ((g + 3) >> 1) <= uu) ++g;
    while (((g + 1) >> 1) * ((g + 2) >> 1) > uu) --g;
    ch = uu - ((g + 1) >> 1) * ((g + 2) >> 1);
  } else { g = blockIdx.x; b = blockIdx.y; ch = 0; }
  const int T = 2 * (g + 1);
  const int c0 = ch * 4;
  const int c1 = (!split || c0 + 4 > T) ? T : c0 + 4;
  const int nch = split ? ((g >> 1) + 1) : 1;
  const int qw = g * 128 + w * 32;

  const short* Kb = Kg + (size_t)b * 4096 * 64;
  const short* Vb = Vt + (size_t)b * 64 * 4096;

  short8 aq[2][2];
#pragma unroll
  for (int qf = 0; qf < 2; ++qf) {
    const short* qp = Qg + (size_t)(b * 4096 + qw + qf * 16 + c) * 64 + sl * 8;
    aq[qf][0] = *(const short8*)(qp);
    aq[qf][1] = *(const short8*)(qp + 32);
  }

  float4v o[2][4];
#pragma unroll
  for (int qf = 0; qf < 2; ++qf)
#pragma unroll
    for (int ht = 0; ht < 4; ++ht) o[qf][ht] = (float4v){0.f, 0.f, 0.f, 0.f};
  float lsum[2] = {0.f, 0.f};

#define STAGE(buf, t)                                                        \
  {                                                                          \
    const int kv0s = (t) * 64;                                               \
    _Pragma("unroll")                                                        \
    for (int j = 0; j < 2; ++j) {                                            \
      const int chunk = j * 256 + tid;                                       \
      const int rw = chunk >> 3;                                             \
      const int scol = ((chunk & 7) ^ (rw & 7)) * 8;                         \
      gld_lds16(Ks[buf] + chunk * 8, Kb + (size_t)(kv0s + rw) * 64 + scol);  \
      gld_lds16(Vs[buf] + chunk * 8, Vb + (size_t)rw * 4096 + kv0s + scol);  \
    }                                                                        \
  }

  STAGE(0, c0)
  __syncthreads();

  const int srcA = c + 32 * (sl & 1);
  const int srcB = srcA + 16;

  int cur = 0;
  for (int t = c0; t < c1; ++t) {
    const int kv0 = t * 64;
    if (t + 1 < c1) STAGE(cur ^ 1, t + 1)

    const short* KsC = Ks[cur];
    const short* VsC = Vs[cur];

    float4v s[2][4];
    __builtin_amdgcn_s_setprio(1);
#pragma unroll
    for (int nt = 0; nt < 4; ++nt) {
      const int rw = nt * 16 + c;
      short8 kb0 = *(const short8*)(KsC + rw * 64 + ((sl ^ (rw & 7)) * 8));
      short8 kb1 = *(const short8*)(KsC + rw * 64 + (((sl + 4) ^ (rw & 7)) * 8));
#pragma unroll
      for (int qf = 0; qf < 2; ++qf) {
        float4v z = {0.f, 0.f, 0.f, 0.f};
        z = MFMA16(kb0, aq[qf][0], z);
        z = MFMA16(kb1, aq[qf][1], z);
        s[qf][nt] = z;
      }
    }
    __builtin_amdgcn_s_setprio(0);

    if (kv0 + 63 > qw) {
#pragma unroll
      for (int nt = 0; nt < 4; ++nt)
#pragma unroll
        for (int i = 0; i < 4; ++i) {
          const int kvg = kv0 + nt * 16 + sl * 4 + i;
#pragma unroll
          for (int qf = 0; qf < 2; ++qf) {
            const int qg = qw + qf * 16 + c;
            s[qf][nt][i] = (kvg <= qg) ? s[qf][nt][i] : -1e30f;
          }
        }
    }

    // P = exp2(s) (base-2; ln2 folded into Q scale), in-lane lsum, pack
    uint32_t tpk[2][4][2];
#pragma unroll
    for (int qf = 0; qf < 2; ++qf)
#pragma unroll
      for (int nt = 0; nt < 4; ++nt) {
        const float p0 = exp2f(s[qf][nt][0]);
        const float p1 = exp2f(s[qf][nt][1]);
        const float p2 = exp2f(s[qf][nt][2]);
        const float p3 = exp2f(s[qf][nt][3]);
        lsum[qf] += (p0 + p1) + (p2 + p3);
        tpk[qf][nt][0] = cvtpk(p0, p1);
        tpk[qf][nt][1] = cvtpk(p2, p3);
      }

    short8 ap[2][2];
#pragma unroll
    for (int qf = 0; qf < 2; ++qf)
#pragma unroll
      for (int f = 0; f < 2; ++f) {
        const uint32_t q0a = __shfl((int)tpk[qf][2 * f][0], srcA);
        const uint32_t q0b = __shfl((int)tpk[qf][2 * f + 1][0], srcA);
        const uint32_t q1a = __shfl((int)tpk[qf][2 * f][1], srcA);
        const uint32_t q1b = __shfl((int)tpk[qf][2 * f + 1][1], srcA);
        const uint32_t q2a = __shfl((int)tpk[qf][2 * f][0], srcB);
        const uint32_t q2b = __shfl((int)tpk[qf][2 * f + 1][0], srcB);
        const uint32_t q3a = __shfl((int)tpk[qf][2 * f][1], srcB);
        const uint32_t q3b = __shfl((int)tpk[qf][2 * f + 1][1], srcB);
        const bool lo = (sl < 2);
        union { uint32_t u[4]; short8 s8; } ua;
        ua.u[0] = lo ? q0a : q0b;
        ua.u[1] = lo ? q1a : q1b;
        ua.u[2] = lo ? q2a : q2b;
        ua.u[3] = lo ? q3a : q3b;
        ap[qf][f] = ua.s8;
      }

    __builtin_amdgcn_s_setprio(1);
#pragma unroll
    for (int ht = 0; ht < 4; ++ht) {
      const int rw = ht * 16 + c;
      short8 vb0 = *(const short8*)(VsC + rw * 64 + ((sl ^ (rw & 7)) * 8));
      short8 vb1 = *(const short8*)(VsC + rw * 64 + (((sl + 4) ^ (rw & 7)) * 8));
#pragma unroll
      for (int qf = 0; qf < 2; ++qf) {
        o[qf][ht] = MFMA16(ap[qf][0], vb0, o[qf][ht]);
        o[qf][ht] = MFMA16(ap[qf][1], vb1, o[qf][ht]);
      }
    }
    __builtin_amdgcn_s_setprio(0);

    if (t + 1 < c1) __syncthreads();
    cur ^= 1;
  }
#undef STAGE

  float rsum[2];
#pragma unroll
  for (int qf = 0; qf < 2; ++qf) {
    float r = lsum[qf];
    r += __shfl_xor(r, 16);
    r += __shfl_xor(r, 32);
    rsum[qf] = r;
  }

  if (nch == 1) {
    float inv[2][4];
#pragma unroll
    for (int qf = 0; qf < 2; ++qf)
#pragma unroll
      for (int i = 0; i < 4; ++i)
        inv[qf][i] = 1.0f / __shfl(rsum[qf], sl * 4 + i);
#pragma unroll
    for (int qf = 0; qf < 2; ++qf)
#pragma unroll
      for (int ht = 0; ht < 4; ++ht)
#pragma unroll
        for (int i = 0; i < 4; ++i) {
          const int q = qw + qf * 16 + sl * 4 + i;
          out[(size_t)(b * 4096 + q) * 64 + ht * 16 + c] = o[qf][ht][i] * inv[qf][i];
        }
  } else {
    short* sp = (short*)(part + (size_t)(b * 272 + uu) * SLOT_BYTES);
    float* lp = (float*)(sp + 8192);
#pragma unroll
    for (int qf = 0; qf < 2; ++qf)
#pragma unroll
      for (int ht = 0; ht < 4; ++ht)
#pragma unroll
        for (int i = 0; i < 4; ++i) {
          const int row = w * 32 + qf * 16 + sl * 4 + i;
          sp[row * 64 + ht * 16 + c] = bf16r(o[qf][ht][i]);
        }
    if (sl == 0) {
#pragma unroll
      for (int qf = 0; qf < 2; ++qf)
        lp[w * 32 + qf * 16 + c] = rsum[qf];
    }
  }
}

// ---------------- Kernel 4: split-KV combine, row-split 4x ------------------
__global__ __launch_bounds__(256) void combine_kernel(
    const char* __restrict__ part, float* __restrict__ out) {
  const int g = blockIdx.x;                      // 0..31
  const int b = blockIdx.y;
  const int N = (g >> 1) + 1;
  if (N == 1) return;                            // attn wrote direct
  const int F = ((g + 1) >> 1) * ((g + 2) >> 1);
  const char* base = part + (size_t)(b * 272 + F) * SLOT_BYTES;
  const int r = blockIdx.z * 32 + (threadIdx.x >> 3);   // row 0..127
  const int cb = (threadIdx.x & 7) * 8;                 // col block (8 f32)

  float L = 0.f;
  float acc[8];
#pragma unroll
  for (int k = 0; k < 8; ++k) acc[k] = 0.f;
  for (int i = 0; i < N; ++i) {
    const short* sp = (const short*)(base + (size_t)i * SLOT_BYTES);
    L += ((const float*)(sp + 8192))[r];
    short8 v = *(const short8*)(sp + r * 64 + cb);
#pragma unroll
    for (int j = 0; j < 8; ++j) acc[j] += bf2f(v[j]);
  }
  const float inv = 1.0f / L;
  float* op = out + (size_t)(b * 4096 + g * 128 + r) * 64 + cb;
  float4v r0 = {acc[0] * inv, acc[1] * inv, acc[2] * inv, acc[3] * inv};
  float4v r1 = {acc[4] * inv, acc[5] * inv, acc[6] * inv, acc[7] * inv};
  *(float4v*)(op) = r0;
  *(float4v*)(op + 4) = r1;
}

extern "C" void kernel_launch(void* const* d_in, const int* in_sizes, int n_in,
                              void* d_out, int out_size, void* d_ws, size_t ws_size,
                              hipStream_t stream) {
  const float* x  = (const float*)d_in[0];
  const float* Wk = (const float*)d_in[1];
  const float* Wq = (const float*)d_in[2];
  const float* Wv = (const float*)d_in[3];

  char* ws = (char*)d_ws;
  short* WT = (short*)ws;                                  // 393216 B
  short* Kg = (short*)(ws + 393216);                       // 2 MB
  short* Qg = (short*)(ws + 393216 + 2097152);             // 2 MB
  short* Vt = (short*)(ws + 393216 + 2 * 2097152);         // 2 MB
  const size_t part_off = 393216 + 3 * 2097152;            // 6684672
  char* part = ws + part_off;

  const int split = (ws_size >= part_off + (size_t)1088 * SLOT_BYTES) ? 1 : 0;

  prep_wt<<<dim3(16, 3), dim3(256), 0, stream>>>(Wk, Wq, Wv, WT);
  proj_kernel<<<dim3(512), dim3(512), 0, stream>>>(x, WT, Kg, Qg, Vt);
  attn_kernel<<<split ? dim3(1088) : dim3(32, 4), dim3(256), 0, stream>>>(
      Qg, Kg, Vt, (float*)d_out, part, split);
  if (split)
    combine_kernel<<<dim3(32, 4, 4), dim3(256), 0, stream>>>(part, (float*)d_out);
}